// Round 7
// baseline (788.092 us; speedup 1.0000x reference)
//
#include <hip/hip_runtime.h>
#include <hip/hip_bf16.h>
#include <cstdint>

#define USER_NUM 30000
#define ITEM_NUM 70000
#define NTOT     100000   // USER_NUM + ITEM_NUM

typedef __attribute__((ext_vector_type(8))) short bf16x8;
typedef __attribute__((ext_vector_type(8))) ushort u16x8;
typedef __attribute__((ext_vector_type(4))) float f32x4;

// fp32 -> (hi, lo) bf16 pair via truncation; a ~= hi + lo to ~2^-16 rel.
__device__ __forceinline__ void split2(float x, ushort& h, ushort& l) {
    unsigned u = __builtin_bit_cast(unsigned int, x);
    h = (ushort)(u >> 16);
    float hf = __builtin_bit_cast(float, u & 0xffff0000u);
    float lo = x - hf;
    l = (ushort)(__builtin_bit_cast(unsigned int, lo) >> 16);
}

// async global->LDS DMA, 16 B per lane; lds base is wave-uniform, HW adds lane*16.
__device__ __forceinline__ void async_cp16(const float* g, float* lds) {
    __builtin_amdgcn_global_load_lds(
        (const __attribute__((address_space(1))) unsigned int*)g,
        (__attribute__((address_space(3))) unsigned int*)lds, 16, 0, 0);
}

// ---------------------------------------------------------------------------
// CSR build kernels
// ---------------------------------------------------------------------------

__global__ void hist_rows(const int* __restrict__ erow, int* __restrict__ counts, int nnz) {
    int i = blockIdx.x * blockDim.x + threadIdx.x;
    if (i < nnz) atomicAdd(&counts[erow[i]], 1);
}

__global__ void scan_block(const int* __restrict__ counts, int* __restrict__ row_ptr,
                           int* __restrict__ blk_sums, int n) {
    __shared__ int sd[1024];
    int i = blockIdx.x * 1024 + threadIdx.x;
    int v = (i < n) ? counts[i] : 0;
    sd[threadIdx.x] = v;
    __syncthreads();
    for (int off = 1; off < 1024; off <<= 1) {
        int t = (threadIdx.x >= off) ? sd[threadIdx.x - off] : 0;
        __syncthreads();
        sd[threadIdx.x] += t;
        __syncthreads();
    }
    if (i < n) row_ptr[i] = sd[threadIdx.x] - v;   // block-local exclusive
    if (threadIdx.x == 1023) blk_sums[blockIdx.x] = sd[1023];
}

__global__ void scan_sums(int* __restrict__ blk_sums, int nb) {
    __shared__ int sd[128];
    int v = (threadIdx.x < nb) ? blk_sums[threadIdx.x] : 0;
    sd[threadIdx.x] = v;
    __syncthreads();
    for (int off = 1; off < 128; off <<= 1) {
        int t = (threadIdx.x >= off) ? sd[threadIdx.x - off] : 0;
        __syncthreads();
        sd[threadIdx.x] += t;
        __syncthreads();
    }
    if (threadIdx.x < nb) blk_sums[threadIdx.x] = sd[threadIdx.x] - v;  // exclusive
}

__global__ void scan_add(int* __restrict__ row_ptr, const int* __restrict__ blk_sums,
                         int n, int nnz) {
    int i = blockIdx.x * 1024 + threadIdx.x;
    if (i < n) row_ptr[i] += blk_sums[blockIdx.x];
    if (blockIdx.x == 0 && threadIdx.x == 0) row_ptr[n] = nnz;
}

__global__ void scatter_edges(const int* __restrict__ erow, const int* __restrict__ ecol,
                              const float* __restrict__ eval,
                              const int* __restrict__ row_ptr, int* __restrict__ fill,
                              int* __restrict__ scol, float* __restrict__ sval, int nnz) {
    int i = blockIdx.x * blockDim.x + threadIdx.x;
    if (i >= nnz) return;
    int r = erow[i];
    int pos = row_ptr[r] + atomicAdd(&fill[r], 1);
    scol[pos] = ecol[i];
    sval[pos] = eval[i];
}

// ---------------------------------------------------------------------------
// Pre-split a weight matrix into hi/lo bf16 arrays (done once per launch).
// ---------------------------------------------------------------------------

__global__ void split_w(const float* __restrict__ W, ushort* __restrict__ Wh,
                        ushort* __restrict__ Wl, int n) {
    int i = blockIdx.x * blockDim.x + threadIdx.x;
    if (i >= n) return;
    ushort h, l;
    split2(W[i], h, l);
    Wh[i] = h;
    Wl[i] = l;
}

// ---------------------------------------------------------------------------
// Dual split-bf16 MFMA GEMM, async-DMA double-buffered (m97 skeleton):
//   C1 = A @ W1^T + b1 + b2 ;  C2 = (A @ W1^T) + (A*A) @ W2^T
// A = virtual row-concat [xa ; xb] split at `split`, rows length KK.
// TM=128 (4 waves x 32 rows), TN per template (wave covers full TN), BK=32.
// Raw fp32 A-tiles staged via global_load_lds (16B/lane) into 2x16 KB LDS
// buffers, XOR-swizzled (quad ^= row&7) to kill bank conflicts (DMA can't pad).
// Each wave converts ONLY its own rows to hi/lo bf16 (+ squares) in registers
// right before the MFMAs. W fragments read from global (L1-hot). One barrier
// per K-iter; DMA for tile k+1 issued before compute of tile k.
// ---------------------------------------------------------------------------

template <int TN, int KK>
__global__ __launch_bounds__(256, 4)
void gemm_dual_async(const float* __restrict__ xa, const float* __restrict__ xb, int split,
                     const ushort* __restrict__ W1h, const ushort* __restrict__ W1l,
                     const ushort* __restrict__ W2h, const ushort* __restrict__ W2l,
                     const float* __restrict__ bias1, const float* __restrict__ bias2,
                     float* __restrict__ C1, float* __restrict__ C2,
                     int M, int Nout) {
    constexpr int TM = 128, BK = 32;
    constexpr int NITER = KK / BK;
    constexpr int NI = TN / 16;
    __shared__ float Abuf[2][TM * BK];   // 2 x 16 KB

    const int m0 = blockIdx.y * TM;
    const int n0 = blockIdx.x * TN;
    const int t  = threadIdx.x;
    const int lane = t & 63, w = t >> 6;
    const int lm = lane & 15, lq = lane >> 4;
    const int dr = lane >> 3;     // DMA: row within 8-row chunk
    const int dq = lane & 7;      // DMA: k-quad slot

    f32x4 acc1[2][NI] = {};
    f32x4 acc2[2][NI] = {};

    // per-lane DMA source row pointers for the 4 chunks this wave stages
    const float* dmarow[4];
#pragma unroll
    for (int j = 0; j < 4; ++j) {
        int gm = m0 + w * 32 + j * 8 + dr;
        const float* rp = xa;   // clamp OOB rows to row 0 (valid memory)
        if (gm < M) rp = (gm < split) ? xa + (size_t)gm * KK
                                      : xb + (size_t)(gm - split) * KK;
        dmarow[j] = rp + (dq ^ dr) * 4;   // XOR-swizzled source quad
    }

    auto dma_tile = [&](int it, int buf) {
#pragma unroll
        for (int j = 0; j < 4; ++j)
            async_cp16(dmarow[j] + it * BK,
                       &Abuf[buf][(size_t)(w * 32 + j * 8) * BK]);
    };

    auto compute = [&](int it, int buf) {
#pragma unroll
        for (int mi = 0; mi < 2; ++mi) {
            int rl = w * 32 + mi * 16 + lm;
            const float* bp = &Abuf[buf][(size_t)rl * BK];
            int sw = lm & 7;
            float4 x0 = *(const float4*)(bp + ((2 * lq + 0) ^ sw) * 4);
            float4 x1 = *(const float4*)(bp + ((2 * lq + 1) ^ sw) * 4);
            float f[8] = {x0.x, x0.y, x0.z, x0.w, x1.x, x1.y, x1.z, x1.w};
            ushort ah[8], al[8], qh[8], ql[8];
#pragma unroll
            for (int j = 0; j < 8; ++j) {
                split2(f[j], ah[j], al[j]);
                float sq = f[j] * f[j];
                split2(sq, qh[j], ql[j]);
            }
            bf16x8 vah = *(const bf16x8*)ah;
            bf16x8 vgl = *(const bf16x8*)al;
            bf16x8 vqh = *(const bf16x8*)qh;
            bf16x8 vql = *(const bf16x8*)ql;
#pragma unroll
            for (int ni = 0; ni < NI; ++ni) {
                size_t wo = (size_t)(n0 + ni * 16 + lm) * KK + it * BK + lq * 8;
                bf16x8 b1h = *(const bf16x8*)(W1h + wo);
                bf16x8 b1l = *(const bf16x8*)(W1l + wo);
                bf16x8 b2h = *(const bf16x8*)(W2h + wo);
                bf16x8 b2l = *(const bf16x8*)(W2l + wo);
                acc1[mi][ni] = __builtin_amdgcn_mfma_f32_16x16x32_bf16(vah, b1h, acc1[mi][ni], 0, 0, 0);
                acc1[mi][ni] = __builtin_amdgcn_mfma_f32_16x16x32_bf16(vah, b1l, acc1[mi][ni], 0, 0, 0);
                acc1[mi][ni] = __builtin_amdgcn_mfma_f32_16x16x32_bf16(vgl, b1h, acc1[mi][ni], 0, 0, 0);
                acc2[mi][ni] = __builtin_amdgcn_mfma_f32_16x16x32_bf16(vqh, b2h, acc2[mi][ni], 0, 0, 0);
                acc2[mi][ni] = __builtin_amdgcn_mfma_f32_16x16x32_bf16(vqh, b2l, acc2[mi][ni], 0, 0, 0);
                acc2[mi][ni] = __builtin_amdgcn_mfma_f32_16x16x32_bf16(vql, b2h, acc2[mi][ni], 0, 0, 0);
            }
        }
    };

    dma_tile(0, 0);
    __syncthreads();
    for (int it = 0; it < NITER; ++it) {
        if (it + 1 < NITER) dma_tile(it + 1, (it + 1) & 1);
        compute(it, it & 1);
        __syncthreads();
    }

    // ---- epilogue: C/D layout col=lane&15, row=lq*4+r; biases folded into C1 ----
#pragma unroll
    for (int mi = 0; mi < 2; ++mi)
#pragma unroll
        for (int ni = 0; ni < NI; ++ni)
#pragma unroll
            for (int r = 0; r < 4; ++r) {
                int gm = m0 + w * 32 + mi * 16 + lq * 4 + r;
                int gn = n0 + ni * 16 + lm;
                if (gm < M && gn < Nout) {
                    size_t o = (size_t)gm * Nout + gn;
                    float g1 = acc1[mi][ni][r];
                    C1[o] = g1 + bias1[gn] + bias2[gn];
                    C2[o] = g1 + acc2[mi][ni][r];
                }
            }
}

// ---------------------------------------------------------------------------
// T1 GEMM with fused gather (known-good R6 structure):
//   e1 = relu( [final[u] ; final[it+U]] @ T1_W^T + T1_b ),  K = 896
// ---------------------------------------------------------------------------

template <int TN, int KK>
__global__ __launch_bounds__(256, 4)
void gemm_t1_mfma(const int* __restrict__ userIdx, const int* __restrict__ itemIdx,
                  const float* __restrict__ uEmbd, const float* __restrict__ iEmbd,
                  const float* __restrict__ f1, const float* __restrict__ f2,
                  const ushort* __restrict__ Wh, const ushort* __restrict__ Wl,
                  const float* __restrict__ bias, float* __restrict__ C,
                  int M, int Nout) {
    constexpr int TM = 128, BK = 32, SR = BK + 8;
    constexpr int NITER = KK / BK;            // 28
    constexpr int WTM = 64, WTN = TN / 2;
    constexpr int MI = WTM / 16, NI = WTN / 16;
    __shared__ ushort Ah[TM * SR], Al[TM * SR];

    const int m0 = blockIdx.y * TM;
    const int n0 = blockIdx.x * TN;
    const int t  = threadIdx.x;
    const int lane = t & 63, w = t >> 6;
    const int wm = w & 1, wn = w >> 1;
    const int lm = lane & 15, lq = lane >> 4;

    const int srow = t >> 1, shalf = t & 1;
    const int b = m0 + srow;
    const bool svalid = (b < M);
    int unode = 0, gnode = 0;
    if (svalid) { unode = userIdx[b]; gnode = itemIdx[b] + USER_NUM; }
    const int sbase = srow * SR + shalf * 16;

    f32x4 acc[MI][NI] = {};

    for (int it = 0; it < NITER; ++it) {
        const int k0 = it * BK;
        {
            float4 v[4] = {};
            if (svalid) {
                int c0 = k0 + shalf * 16;
                int node = (c0 < 448) ? unode : gnode;
                int cc = (c0 < 448) ? c0 : c0 - 448;
                const float* p;
                if (cc < 256)
                    p = (node < USER_NUM) ? uEmbd + (size_t)node * 256 + cc
                                          : iEmbd + (size_t)(node - USER_NUM) * 256 + cc;
                else if (cc < 384) p = f1 + (size_t)node * 128 + (cc - 256);
                else               p = f2 + (size_t)node * 64  + (cc - 384);
#pragma unroll
                for (int q = 0; q < 4; ++q) v[q] = *(const float4*)(p + q * 4);
            }
            ushort hb[16], lb[16];
#pragma unroll
            for (int q = 0; q < 4; ++q) {
                const float av[4] = {v[q].x, v[q].y, v[q].z, v[q].w};
#pragma unroll
                for (int j = 0; j < 4; ++j) split2(av[j], hb[q * 4 + j], lb[q * 4 + j]);
            }
            *(u16x8*)(Ah + sbase)     = *(const u16x8*)&hb[0];
            *(u16x8*)(Ah + sbase + 8) = *(const u16x8*)&hb[8];
            *(u16x8*)(Al + sbase)     = *(const u16x8*)&lb[0];
            *(u16x8*)(Al + sbase + 8) = *(const u16x8*)&lb[8];
        }
        __syncthreads();

        bf16x8 bh[NI], bl[NI];
#pragma unroll
        for (int ni = 0; ni < NI; ++ni) {
            size_t wo = (size_t)(n0 + wn * WTN + ni * 16 + lm) * KK + k0 + lq * 8;
            bh[ni] = *(const bf16x8*)(Wh + wo);
            bl[ni] = *(const bf16x8*)(Wl + wo);
        }
#pragma unroll
        for (int mi = 0; mi < MI; ++mi) {
            int off = (wm * WTM + mi * 16 + lm) * SR + lq * 8;
            bf16x8 ah = *(const bf16x8*)(Ah + off);
            bf16x8 al = *(const bf16x8*)(Al + off);
#pragma unroll
            for (int ni = 0; ni < NI; ++ni) {
                acc[mi][ni] = __builtin_amdgcn_mfma_f32_16x16x32_bf16(ah, bh[ni], acc[mi][ni], 0, 0, 0);
                acc[mi][ni] = __builtin_amdgcn_mfma_f32_16x16x32_bf16(ah, bl[ni], acc[mi][ni], 0, 0, 0);
                acc[mi][ni] = __builtin_amdgcn_mfma_f32_16x16x32_bf16(al, bh[ni], acc[mi][ni], 0, 0, 0);
            }
        }
        __syncthreads();
    }

#pragma unroll
    for (int mi = 0; mi < MI; ++mi)
#pragma unroll
        for (int ni = 0; ni < NI; ++ni)
#pragma unroll
            for (int r = 0; r < 4; ++r) {
                int gm = m0 + wm * WTM + mi * 16 + lq * 4 + r;
                int gn = n0 + wn * WTN + ni * 16 + lm;
                if (gm < M && gn < Nout)
                    C[(size_t)gm * Nout + gn] = fmaxf(acc[mi][ni][r] + bias[gn], 0.f);
            }
}

// ---------------------------------------------------------------------------
// Fused SPMM epilogue (biases pre-folded into G1):
//   out[r,:] = sum_e val_e * H[col_e,:] + G1[r,:]
// 4 rows per 256-thread block, one wave per row, VEC floats per lane.
// ---------------------------------------------------------------------------

template <int VEC>
__global__ __launch_bounds__(256)
void spmm_fused(const int* __restrict__ row_ptr, const int* __restrict__ scol,
                const float* __restrict__ sval, const float* __restrict__ H,
                const float* __restrict__ G1, float* __restrict__ out, int n) {
    constexpr int W = 64 * VEC;
    int r = blockIdx.x * 4 + (threadIdx.x >> 6);
    if (r >= n) return;
    int base = (threadIdx.x & 63) * VEC;
    float acc[VEC];
    const float* g = G1 + (size_t)r * W + base;
#pragma unroll
    for (int v = 0; v < VEC; ++v) acc[v] = g[v];
    int e0 = row_ptr[r], e1 = row_ptr[r + 1];
    for (int e = e0; e < e1; ++e) {
        int c = scol[e];
        float val = sval[e];
        const float* h = H + (size_t)c * W + base;
#pragma unroll
        for (int v = 0; v < VEC; ++v) acc[v] += val * h[v];
    }
    float* o = out + (size_t)r * W + base;
#pragma unroll
    for (int v = 0; v < VEC; ++v) o[v] = acc[v];
}

// ---------------------------------------------------------------------------
// Fused T2+T3 tail: out[b] = T3_W . relu(T2_W @ e1[b] + T2_b) + T3_b
// ---------------------------------------------------------------------------

__global__ __launch_bounds__(256)
void mlp_tail(const float* __restrict__ e1, const float* __restrict__ T2_W,
              const float* __restrict__ T2_b, const float* __restrict__ T3_W,
              const float* __restrict__ T3_b, float* __restrict__ out, int B) {
    int wid = (blockIdx.x * 256 + threadIdx.x) >> 6;
    if (wid >= B) return;
    int lane = threadIdx.x & 63;
    float s = 0.f;
    if (lane < 32) {
        const float* er = e1 + (size_t)wid * 64;
        const float* wr = T2_W + lane * 64;
        float d = T2_b[lane];
#pragma unroll
        for (int k = 0; k < 64; ++k) d += er[k] * wr[k];
        s = fmaxf(d, 0.f) * T3_W[lane];
    }
#pragma unroll
    for (int off2 = 16; off2 > 0; off2 >>= 1) s += __shfl_down(s, off2);
    if (lane == 0) out[wid] = s + T3_b[0];
}

// ---------------------------------------------------------------------------

extern "C" void kernel_launch(void* const* d_in, const int* in_sizes, int n_in,
                              void* d_out, int out_size, void* d_ws, size_t ws_size,
                              hipStream_t stream) {
    const int* userIdx  = (const int*)d_in[0];
    const int* itemIdx  = (const int*)d_in[1];
    const int* edge_row = (const int*)d_in[2];
    const int* edge_col = (const int*)d_in[3];
    const float* edge_val = (const float*)d_in[4];
    const float* uEmbd  = (const float*)d_in[5];
    const float* iEmbd  = (const float*)d_in[6];
    const float* W1_0 = (const float*)d_in[7];
    const float* b1_0 = (const float*)d_in[8];
    const float* W2_0 = (const float*)d_in[9];
    const float* b2_0 = (const float*)d_in[10];
    const float* W1_1 = (const float*)d_in[11];
    const float* b1_1 = (const float*)d_in[12];
    const float* W2_1 = (const float*)d_in[13];
    const float* b2_1 = (const float*)d_in[14];
    const float* T1_W = (const float*)d_in[15];
    const float* T1_b = (const float*)d_in[16];
    const float* T2_W = (const float*)d_in[17];
    const float* T2_b = (const float*)d_in[18];
    const float* T3_W = (const float*)d_in[19];
    const float* T3_b = (const float*)d_in[20];
    float* out = (float*)d_out;

    const int B   = in_sizes[0];
    const int NNZ = in_sizes[2];
    const int N   = NTOT;

    // ---- workspace carve-up (bytes, 256-aligned) ----
    uint8_t* ws = (uint8_t*)d_ws;
    size_t off = 0;
    auto alloc = [&](size_t bytes) {
        void* p = ws + off;
        off += (bytes + 255) & ~(size_t)255;
        return p;
    };
    float* bufA = (float*)alloc((size_t)N * 128 * 4);  // G1_0; later G1_1 | H_1
    float* bufB = (float*)alloc((size_t)N * 128 * 4);  // H_0;  later f2
    float* f1   = (float*)alloc((size_t)N * 128 * 4);
    float* e1   = (float*)alloc((size_t)B * 64 * 4);
    int*   counts  = (int*)alloc((size_t)2 * N * 4);   // counts[N] + fill[N]
    int*   fill    = counts + N;
    int*   row_ptr = (int*)alloc((size_t)(N + 1) * 4);
    int*   blk_sums= (int*)alloc(128 * 4);
    int*   scol    = (int*)alloc((size_t)NNZ * 4);
    float* sval    = (float*)alloc((size_t)NNZ * 4);
    // pre-split weight matrices (hi/lo bf16 stored as ushort)
    ushort* W10h = (ushort*)alloc(128 * 256 * 2);
    ushort* W10l = (ushort*)alloc(128 * 256 * 2);
    ushort* W20h = (ushort*)alloc(128 * 256 * 2);
    ushort* W20l = (ushort*)alloc(128 * 256 * 2);
    ushort* W11h = (ushort*)alloc(64 * 128 * 2);
    ushort* W11l = (ushort*)alloc(64 * 128 * 2);
    ushort* W21h = (ushort*)alloc(64 * 128 * 2);
    ushort* W21l = (ushort*)alloc(64 * 128 * 2);
    ushort* T1h  = (ushort*)alloc(64 * 896 * 2);
    ushort* T1l  = (ushort*)alloc(64 * 896 * 2);
    (void)ws_size; (void)n_in; (void)out_size;

    float* G1_0 = bufA;
    float* H_0  = bufB;
    float* G1_1 = bufA;
    float* H_1  = bufA + (size_t)N * 64;
    float* f2   = bufB;

    // ---- build CSR ----
    hipMemsetAsync(counts, 0, (size_t)2 * N * 4, stream);
    hist_rows<<<(NNZ + 255) / 256, 256, 0, stream>>>(edge_row, counts, NNZ);
    int nb = (N + 1023) / 1024;   // 98
    scan_block<<<nb, 1024, 0, stream>>>(counts, row_ptr, blk_sums, N);
    scan_sums<<<1, 128, 0, stream>>>(blk_sums, nb);
    scan_add<<<nb, 1024, 0, stream>>>(row_ptr, blk_sums, N, NNZ);
    scatter_edges<<<(NNZ + 255) / 256, 256, 0, stream>>>(edge_row, edge_col, edge_val,
                                                         row_ptr, fill, scol, sval, NNZ);

    // ---- pre-split weights ----
    split_w<<<(32768 + 255) / 256, 256, 0, stream>>>(W1_0, W10h, W10l, 32768);
    split_w<<<(32768 + 255) / 256, 256, 0, stream>>>(W2_0, W20h, W20l, 32768);
    split_w<<<(8192 + 255) / 256, 256, 0, stream>>>(W1_1, W11h, W11l, 8192);
    split_w<<<(8192 + 255) / 256, 256, 0, stream>>>(W2_1, W21h, W21l, 8192);
    split_w<<<(57344 + 255) / 256, 256, 0, stream>>>(T1_W, T1h, T1l, 57344);

    // ---- layer 0: G1_0 = F@W1_0^T (+biases), H_0 = F@W1_0^T + (F*F)@W2_0^T ----
    {
        dim3 grid(2, (N + 127) / 128);   // TN=64, Nout=128
        gemm_dual_async<64, 256><<<grid, 256, 0, stream>>>(
            uEmbd, iEmbd, USER_NUM, W10h, W10l, W20h, W20l, b1_0, b2_0, G1_0, H_0, N, 128);
    }
    // f1 = spmm(H_0) + G1_0   (biases already in G1_0)
    spmm_fused<2><<<(N + 3) / 4, 256, 0, stream>>>(row_ptr, scol, sval, H_0, G1_0, f1, N);

    // ---- layer 1: G1_1 = f1@W1_1^T (+biases), H_1 = f1@W1_1^T + (f1*f1)@W2_1^T ----
    {
        dim3 grid(1, (N + 127) / 128);   // TN=64, Nout=64
        gemm_dual_async<64, 128><<<grid, 256, 0, stream>>>(
            f1, f1, N, W11h, W11l, W21h, W21l, b1_1, b2_1, G1_1, H_1, N, 64);
    }
    // f2 = spmm(H_1) + G1_1
    spmm_fused<1><<<(N + 3) / 4, 256, 0, stream>>>(row_ptr, scol, sval, H_1, G1_1, f2, N);

    // ---- fused gather + T1 GEMM, then fused T2+T3 tail ----
    {
        dim3 grid(1, (B + 127) / 128);   // TN=64, K=896
        gemm_t1_mfma<64, 896><<<grid, 256, 0, stream>>>(
            userIdx, itemIdx, uEmbd, iEmbd, f1, f2, T1h, T1l, T1_b, e1, B, 64);
    }
    mlp_tail<<<(B * 64 + 255) / 256, 256, 0, stream>>>(e1, T2_W, T2_b, T3_W, T3_b, out, B);
}